// Round 1
// baseline (345.966 us; speedup 1.0000x reference)
//
#include <hip/hip_runtime.h>
#include <hip/hip_bf16.h>

// LocallyConnected2d: x(32,48,64,64) f32, weight(48,64,64,48,3,3) f32, bias(48) f32
// out(32,48,64,64) f32.  Per-location GEMM M=32(b) x N=48(o) x K=432, bf16 MFMA.

#define NB 32      // batch
#define NC 48      // in channels
#define NO 48      // out channels
#define NH 64
#define NW 64
#define NL 4096    // 64*64 locations
#define NK 432     // 48*9
#define KP 448     // K padded to 14*32
#define PITCH 456  // LDS row pitch in bf16 (912 B, 16B-multiple)
#define NTHREADS 384

typedef __bf16 bf16x8 __attribute__((ext_vector_type(8)));
typedef __bf16 bf16x4 __attribute__((ext_vector_type(4)));
typedef float f32x4 __attribute__((ext_vector_type(4)));

__global__ __launch_bounds__(NTHREADS)
void lc2d_kernel(const float* __restrict__ x, const float* __restrict__ wgt,
                 const float* __restrict__ bias, float* __restrict__ out) {
    __shared__ __bf16 xs[NB * PITCH];   // 29184 B
    __shared__ __bf16 ws[NO * PITCH];   // 43776 B   total 72960 B -> 2 blocks/CU

    const int t = threadIdx.x;
    const int bid = blockIdx.x;
    // chunked XCD swizzle: each XCD gets 512 consecutive locations (8 h-rows)
    const int l = (bid & 7) * 512 + (bid >> 3);
    const int h = l >> 6;
    const int w = l & 63;

    // ---- zero the K-pad region [NK, PITCH) of all 80 rows (24 bf16 = 6 x bf16x4)
    for (int idx = t; idx < 80 * 6; idx += NTHREADS) {
        const int row = idx / 6, chunk = idx % 6;
        __bf16* p = (row < NB) ? &xs[row * PITCH + NK + chunk * 4]
                               : &ws[(row - NB) * PITCH + NK + chunk * 4];
        bf16x4 z = {(__bf16)0.f, (__bf16)0.f, (__bf16)0.f, (__bf16)0.f};
        *(bf16x4*)p = z;
    }

    // ---- stage weights: 48 rows of 432 contiguous floats -> bf16 LDS
    // 48*108 = 5184 float4 chunks, coalesced (adjacent threads = adjacent 16B)
    for (int idx = t; idx < NO * 108; idx += NTHREADS) {
        const int o = idx / 108, ch = idx % 108;
        const float4 v = *(const float4*)(wgt + ((size_t)o * NL + l) * NK + (size_t)ch * 4);
        bf16x4 bv;
        bv[0] = (__bf16)v.x; bv[1] = (__bf16)v.y; bv[2] = (__bf16)v.z; bv[3] = (__bf16)v.w;
        *(bf16x4*)&ws[o * PITCH + ch * 4] = bv;
    }

    // ---- stage x patches: task (b,c) copies its 3x3 window (k = c*9 + di*3 + dj)
    for (int idx = t; idx < NB * NC; idx += NTHREADS) {
        const int b = idx / NC, c = idx % NC;
        const float* xb = x + ((size_t)(b * NC + c)) * (NH * NW);
        __bf16* dst = &xs[b * PITCH + c * 9];
#pragma unroll
        for (int di = 0; di < 3; ++di) {
            const int y = h + di - 1;
            const bool yok = (unsigned)y < NH;
#pragma unroll
            for (int dj = 0; dj < 3; ++dj) {
                const int xc = w + dj - 1;
                const float v = (yok && (unsigned)xc < NW) ? xb[y * NW + xc] : 0.0f;
                dst[di * 3 + dj] = (__bf16)v;
            }
        }
    }

    __syncthreads();

    // ---- compute: 6 waves, each owns a 16x16 C-tile (mt: b-half, ot: o-third)
    const int lane = t & 63, wid = t >> 6;
    const int mt = wid & 1, ot = wid >> 1;
    const int rrow = lane & 15, g = lane >> 4;

    const __bf16* pa = &xs[(mt * 16 + rrow) * PITCH + g * 8];
    const __bf16* pb = &ws[(ot * 16 + rrow) * PITCH + g * 8];

    f32x4 acc = {0.f, 0.f, 0.f, 0.f};
#pragma unroll
    for (int ks = 0; ks < KP / 32; ++ks) {
        bf16x8 av = *(const bf16x8*)(pa + ks * 32);
        bf16x8 bv = *(const bf16x8*)(pb + ks * 32);
        acc = __builtin_amdgcn_mfma_f32_16x16x32_bf16(av, bv, acc, 0, 0, 0);
    }

    // ---- epilogue: C layout col(lane&15)=o, row((lane>>4)*4+r)=b
    const int o = ot * 16 + rrow;
    const float bsv = bias[o];
#pragma unroll
    for (int r = 0; r < 4; ++r) {
        const int b = mt * 16 + g * 4 + r;
        out[((size_t)(b * NO + o)) * NL + l] = acc[r] + bsv;
    }
}

extern "C" void kernel_launch(void* const* d_in, const int* in_sizes, int n_in,
                              void* d_out, int out_size, void* d_ws, size_t ws_size,
                              hipStream_t stream) {
    const float* x    = (const float*)d_in[0];
    const float* wgt  = (const float*)d_in[1];
    const float* bias = (const float*)d_in[2];
    float* out = (float*)d_out;
    lc2d_kernel<<<dim3(NL), dim3(NTHREADS), 0, stream>>>(x, wgt, bias, out);
}

// Round 2
// 293.226 us; speedup vs baseline: 1.1799x; 1.1799x over previous
//
#include <hip/hip_runtime.h>
#include <hip/hip_bf16.h>

// LocallyConnected2d: x(32,48,64,64) f32, weight(48,64,64,48,3,3) f32, bias(48) f32
// out(32,48,64,64) f32.  Per-location GEMM M=32(b) x N=48(o) x K=432, bf16 MFMA.
//
// R2 structure: weights NOT staged in LDS (zero reuse) -> loaded global->reg
// per-wave with depth-2 prefetch; LDS only for x patches (29 KB -> 5 blocks/CU).

#define NB 32      // batch
#define NC 48      // in channels
#define NO 48      // out channels
#define NH 64
#define NW 64
#define NL 4096    // 64*64 locations
#define NK 432     // 48*9
#define PITCH 456  // LDS row pitch in bf16 (912 B)
#define NTHREADS 192

typedef __bf16 bf16x8 __attribute__((ext_vector_type(8)));
typedef float f32x4 __attribute__((ext_vector_type(4)));

__global__ __launch_bounds__(NTHREADS, 4)
void lc2d_kernel(const float* __restrict__ x, const float* __restrict__ wgt,
                 const float* __restrict__ bias, float* __restrict__ out) {
    __shared__ __bf16 xs[NB * PITCH];   // 29184 B -> 5 blocks/CU

    const int t = threadIdx.x;
    const int bid = blockIdx.x;
    // chunked XCD swizzle: each XCD gets 512 consecutive locations (8 h-rows)
    const int l = (bid & 7) * 512 + (bid >> 3);
    const int h = l >> 6;
    const int w = l & 63;

    // ---- zero the K-pad region [432, 456) of all 32 rows: 32 rows x 3 bf16x8
    if (t < 96) {
        const int row = t & 31, chunk = t >> 5;
        bf16x8 z = {};
        *(bf16x8*)&xs[row * PITCH + NK + chunk * 8] = z;
    }

    // ---- stage x patches: task (b,c) copies its 3x3 window (k = c*9 + di*3 + dj)
    // 1536 tasks / 192 threads = 8 iterations; loads hoisted to regs for MLP.
#pragma unroll 2
    for (int it = 0; it < 8; ++it) {
        const int idx = t + it * NTHREADS;
        const int b = idx / NC, c = idx - b * NC;
        const float* xb = x + ((size_t)(b * NC + c)) * (NH * NW);
        float v[9];
#pragma unroll
        for (int di = 0; di < 3; ++di) {
            const int y = h + di - 1;
            const bool yok = (unsigned)y < (unsigned)NH;
#pragma unroll
            for (int dj = 0; dj < 3; ++dj) {
                const int xc = w + dj - 1;
                v[di * 3 + dj] = (yok && (unsigned)xc < (unsigned)NW) ? xb[y * NW + xc] : 0.0f;
            }
        }
        __bf16* dst = &xs[b * PITCH + c * 9];
#pragma unroll
        for (int k9 = 0; k9 < 9; ++k9) dst[k9] = (__bf16)v[k9];
    }

    __syncthreads();

    // ---- compute: 3 waves, wave = one o-third; each wave does BOTH b-half tiles
    const int lane = t & 63, wid = t >> 6;      // wid = ot (0..2)
    const int rrow = lane & 15, g = lane >> 4;
    const int o = wid * 16 + rrow;

    const float* wp = wgt + ((size_t)o * NL + l) * NK + g * 8;
    const __bf16* pa0 = &xs[rrow * PITCH + g * 8];          // b 0..15
    const __bf16* pa1 = &xs[(16 + rrow) * PITCH + g * 8];   // b 16..31

    f32x4 acc0 = {0.f, 0.f, 0.f, 0.f};
    f32x4 acc1 = {0.f, 0.f, 0.f, 0.f};

    // depth-2 prefetch: B fragment for ks in flight while computing ks-1
    float4 f0 = *(const float4*)(wp);
    float4 f1 = *(const float4*)(wp + 4);

#pragma unroll
    for (int ks = 0; ks < 14; ++ks) {
        float4 n0 = {0.f, 0.f, 0.f, 0.f}, n1 = {0.f, 0.f, 0.f, 0.f};
        if (ks < 13) {
            const float* np = wp + (ks + 1) * 32;
            if (ks + 1 == 13) {
                // k = 416 + g*8 .. : g>=2 maps to k>=432 (pad) -> stay zero
                if (g < 2) { n0 = *(const float4*)np; n1 = *(const float4*)(np + 4); }
            } else {
                n0 = *(const float4*)np; n1 = *(const float4*)(np + 4);
            }
        }
        bf16x8 av0 = *(const bf16x8*)(pa0 + ks * 32);
        bf16x8 av1 = *(const bf16x8*)(pa1 + ks * 32);
        bf16x8 bv;
        bv[0] = (__bf16)f0.x; bv[1] = (__bf16)f0.y; bv[2] = (__bf16)f0.z; bv[3] = (__bf16)f0.w;
        bv[4] = (__bf16)f1.x; bv[5] = (__bf16)f1.y; bv[6] = (__bf16)f1.z; bv[7] = (__bf16)f1.w;
        acc0 = __builtin_amdgcn_mfma_f32_16x16x32_bf16(av0, bv, acc0, 0, 0, 0);
        acc1 = __builtin_amdgcn_mfma_f32_16x16x32_bf16(av1, bv, acc1, 0, 0, 0);
        f0 = n0; f1 = n1;
    }

    // ---- epilogue: C layout col(lane&15)=o, row((lane>>4)*4+r)=b
    const float bsv = bias[o];
#pragma unroll
    for (int r = 0; r < 4; ++r) {
        const int b0 = g * 4 + r;
        out[((size_t)(b0 * NO + o)) * NL + l] = acc0[r] + bsv;
        out[((size_t)((16 + b0) * NO + o)) * NL + l] = acc1[r] + bsv;
    }
}

extern "C" void kernel_launch(void* const* d_in, const int* in_sizes, int n_in,
                              void* d_out, int out_size, void* d_ws, size_t ws_size,
                              hipStream_t stream) {
    const float* x    = (const float*)d_in[0];
    const float* wgt  = (const float*)d_in[1];
    const float* bias = (const float*)d_in[2];
    float* out = (float*)d_out;
    lc2d_kernel<<<dim3(NL), dim3(NTHREADS), 0, stream>>>(x, wgt, bias, out);
}